// Round 10
// baseline (94.480 us; speedup 1.0000x reference)
//
#include <hip/hip_runtime.h>

#define B 64
#define L 1024
#define H 768
#define NROWS (B * L)
#define LOG2E 1.4426950408889634f
#define CS 16
#define NCH 64
#define NG 16

#define EXP2(x) __builtin_amdgcn_exp2f(x)
#define LOG2(x) __builtin_amdgcn_logf(x)

// Exact power-of-2 renormalization: value = p * 2^lc kept invariant.
__device__ __forceinline__ void renorm4(float& x0, float& x1, float& x2, float& x3, float& lc) {
    const float g = fmaxf(fmaxf(x0, x1), fmaxf(x2, x3));
    const int e = (__float_as_int(g) >> 23) & 255;
    const float s = __int_as_float((254 - e) << 23);
    x0 *= s; x1 *= s; x2 *= s; x3 *= s;
    lc += (float)(e - 127);
}

// ---------------- Kernel 1: pfeatsT[l][b][k] = 2^((hidden.w + bias) * log2e)
__global__ __launch_bounds__(256) void feats_kernel(
    const float* __restrict__ hidden, const float* __restrict__ w,
    const float* __restrict__ bias, float4* __restrict__ pfeatsT)
{
    const int lane = threadIdx.x & 63;
    const int wave = (blockIdx.x * blockDim.x + threadIdx.x) >> 6;
    const int nwaves = (gridDim.x * blockDim.x) >> 6;

    float wr[3][4][4];
#pragma unroll
    for (int c = 0; c < 3; ++c)
#pragma unroll
        for (int j = 0; j < 4; ++j)
#pragma unroll
            for (int k = 0; k < 4; ++k)
                wr[c][j][k] = w[k * H + lane * 4 + 256 * c + j];
    const float bb0 = bias[0], bb1 = bias[1], bb2 = bias[2], bb3 = bias[3];

    for (int row = wave; row < NROWS; row += nwaves) {
        const float4* hrow = reinterpret_cast<const float4*>(hidden) + (size_t)row * (H / 4);
        float acc[4] = {0.f, 0.f, 0.f, 0.f};
#pragma unroll
        for (int c = 0; c < 3; ++c) {
            float4 h = hrow[lane + 64 * c];
            const float hv[4] = {h.x, h.y, h.z, h.w};
#pragma unroll
            for (int j = 0; j < 4; ++j)
#pragma unroll
                for (int k = 0; k < 4; ++k)
                    acc[k] = fmaf(hv[j], wr[c][j][k], acc[k]);
        }
#pragma unroll
        for (int k = 0; k < 4; ++k) {
            float v = acc[k];
#pragma unroll
            for (int s = 32; s >= 1; s >>= 1) v += __shfl_xor(v, s, 64);
            acc[k] = v;
        }
        if (lane == 0) {
            const int b = row >> 10, l = row & 1023;
            pfeatsT[l * B + b] = make_float4(EXP2((acc[0] + bb0) * LOG2E),
                                             EXP2((acc[1] + bb1) * LOG2E),
                                             EXP2((acc[2] + bb2) * LOG2E),
                                             EXP2((acc[3] + bb3) * LOG2E));
        }
    }
}

// ---------------- Kernel 2: per-chunk 4x4 transfer matrices in PROB space
__global__ __launch_bounds__(128) void chunkmat_kernel(
    const float4* __restrict__ pfeatsT, const int* __restrict__ seq_lens,
    const float* __restrict__ T, float* __restrict__ mats_p,
    float* __restrict__ mats_lc)
{
    const int b = threadIdx.x & 63;
    const int dir = threadIdx.x >> 6;
    const int c = blockIdx.x;
    const int sl = seq_lens[b];
    const int lo = c * CS + 1;
    const int hi = min(c * CS + CS, L - 1);
    const int ns = hi - lo + 1;

    float eT2[4][4];
#pragma unroll
    for (int i = 0; i < 4; ++i)
#pragma unroll
        for (int j = 0; j < 4; ++j) eT2[i][j] = EXP2(T[i * 4 + j] * LOG2E);

    float4 fr[CS];
#pragma unroll
    for (int u = 0; u < CS; ++u) {
        const int t = dir ? max(hi - u, lo) : min(lo + u, hi);
        fr[u] = pfeatsT[t * B + b];
    }

    float M[4][4];
#pragma unroll
    for (int i = 0; i < 4; ++i)
#pragma unroll
        for (int j = 0; j < 4; ++j) M[i][j] = (i == j) ? 1.f : 0.f;
    float lc = 0.f;

#pragma unroll
    for (int u = 0; u < CS; ++u) {
        const int pos = dir ? (hi - u) : (lo + u);
        const bool valid = (u < ns) && (pos < sl);
        const float f[4] = {fr[u].x, fr[u].y, fr[u].z, fr[u].w};
        float nM[4][4];
        if (dir == 0) {
#pragma unroll
            for (int i = 0; i < 4; ++i)
#pragma unroll
                for (int j = 0; j < 4; ++j) {
                    const float s = (M[i][0] * eT2[0][j] + M[i][1] * eT2[1][j]) +
                                    (M[i][2] * eT2[2][j] + M[i][3] * eT2[3][j]);
                    nM[i][j] = s * f[j];
                }
        } else {
            float Mg[4][4];
#pragma unroll
            for (int k = 0; k < 4; ++k)
#pragma unroll
                for (int j = 0; j < 4; ++j) Mg[k][j] = f[k] * M[k][j];
#pragma unroll
            for (int i = 0; i < 4; ++i)
#pragma unroll
                for (int j = 0; j < 4; ++j)
                    nM[i][j] = (eT2[i][0] * Mg[0][j] + eT2[i][1] * Mg[1][j]) +
                               (eT2[i][2] * Mg[2][j] + eT2[i][3] * Mg[3][j]);
        }
#pragma unroll
        for (int i = 0; i < 4; ++i)
#pragma unroll
            for (int j = 0; j < 4; ++j) M[i][j] = valid ? nM[i][j] : M[i][j];

        if (u == 7 || u == CS - 1) {
            float g = 0.f;
#pragma unroll
            for (int i = 0; i < 4; ++i)
#pragma unroll
                for (int j = 0; j < 4; ++j) g = fmaxf(g, M[i][j]);
            const int e = (__float_as_int(g) >> 23) & 255;
            const float s = __int_as_float((254 - e) << 23);
#pragma unroll
            for (int i = 0; i < 4; ++i)
#pragma unroll
                for (int j = 0; j < 4; ++j) M[i][j] *= s;
            lc += (float)(e - 127);
        }
    }
#pragma unroll
    for (int i = 0; i < 4; ++i)
#pragma unroll
        for (int j = 0; j < 4; ++j)
            mats_p[((dir * NCH + c) * 16 + i * 4 + j) * B + b] = M[i][j];
    mats_lc[(dir * NCH + c) * B + b] = lc;
}

// ---------------- Kernel 3 (fused): phase A compose supermats (parallel) ->
// phase B serial 16-step scan (threads 0..127, group bounds in LDS) ->
// phase C expand group bounds to all 64 chunk vbounds (parallel)
__global__ __launch_bounds__(1024) void bound2_kernel(
    const float4* __restrict__ pfeatsT, const float* __restrict__ mats_p,
    const float* __restrict__ mats_lc, float* __restrict__ smats_p,
    float* __restrict__ smats_lc, float* __restrict__ vbound_p,
    float* __restrict__ vbound_lc, float* __restrict__ logZ)
{
    const int tid = threadIdx.x;

    __shared__ float gb_p[2 * NG * 4 * B];   // 32 KB
    __shared__ float gb_lc[2 * NG * B];      // 8 KB

    // ===== Phase A: supermat for (b, dir, g) and (b, dir, g+8) =====
    {
        const int b = tid & 63;
        const int dir = (tid >> 6) & 1;
        const int g0 = tid >> 7; // 0..7
#pragma unroll
        for (int gg = 0; gg < 2; ++gg) {
            const int g = g0 + 8 * gg;
            float P[4][4];
            float lc;
            {
                const int c0 = 4 * g;
#pragma unroll
                for (int k = 0; k < 16; ++k)
                    P[k >> 2][k & 3] = mats_p[((dir * NCH + c0) * 16 + k) * B + b];
                lc = mats_lc[(dir * NCH + c0) * B + b];
            }
#pragma unroll
            for (int q = 1; q < 4; ++q) {
                const int c = 4 * g + q;
                float Q[4][4];
#pragma unroll
                for (int k = 0; k < 16; ++k)
                    Q[k >> 2][k & 3] = mats_p[((dir * NCH + c) * 16 + k) * B + b];
                lc += mats_lc[(dir * NCH + c) * B + b];

                float R[4][4];
#pragma unroll
                for (int i = 0; i < 4; ++i)
#pragma unroll
                    for (int j = 0; j < 4; ++j)
                        R[i][j] = (P[i][0] * Q[0][j] + P[i][1] * Q[1][j]) +
                                  (P[i][2] * Q[2][j] + P[i][3] * Q[3][j]);

                float gmax = 0.f;
#pragma unroll
                for (int i = 0; i < 4; ++i)
#pragma unroll
                    for (int j = 0; j < 4; ++j) gmax = fmaxf(gmax, R[i][j]);
                const int e = (__float_as_int(gmax) >> 23) & 255;
                const float s = __int_as_float((254 - e) << 23);
#pragma unroll
                for (int i = 0; i < 4; ++i)
#pragma unroll
                    for (int j = 0; j < 4; ++j) P[i][j] = R[i][j] * s;
                lc += (float)(e - 127);
            }
#pragma unroll
            for (int i = 0; i < 4; ++i)
#pragma unroll
                for (int j = 0; j < 4; ++j)
                    smats_p[((dir * NG + g) * 16 + i * 4 + j) * B + b] = P[i][j];
            smats_lc[(dir * NG + g) * B + b] = lc;
        }
    }

    __syncthreads();

    // ===== Phase B: serial scan over 16 supermats (threads 0..127) =====
    if (tid < 128) {
        const int b = tid & 63;
        const int dir = tid >> 6;

        float Ms[4][17];
#pragma unroll
        for (int p = 0; p < 3; ++p) {
            const int cc = dir ? (NG - 1 - p) : p;
#pragma unroll
            for (int k = 0; k < 16; ++k)
                Ms[p][k] = smats_p[((dir * NG + cc) * 16 + k) * B + b];
            Ms[p][16] = smats_lc[(dir * NG + cc) * B + b];
        }

        float v0, v1, v2, v3, vlc = 0.f;
        if (dir == 0) {
            const float4 f0 = pfeatsT[b];
            v0 = f0.x; v1 = f0.y; v2 = f0.z; v3 = f0.w;
        } else {
            v0 = v1 = v2 = v3 = 1.f;
        }

#pragma unroll
        for (int u = 0; u < NG; ++u) {
            const int cc = dir ? (NG - 1 - u) : u;
            gb_p[((dir * NG + cc) * 4 + 0) * B + b] = v0;
            gb_p[((dir * NG + cc) * 4 + 1) * B + b] = v1;
            gb_p[((dir * NG + cc) * 4 + 2) * B + b] = v2;
            gb_p[((dir * NG + cc) * 4 + 3) * B + b] = v3;
            gb_lc[(dir * NG + cc) * B + b] = vlc;
            if (u + 3 < NG) {
                const int cp = dir ? (NG - 1 - (u + 3)) : (u + 3);
#pragma unroll
                for (int k = 0; k < 16; ++k)
                    Ms[(u + 3) & 3][k] = smats_p[((dir * NG + cp) * 16 + k) * B + b];
                Ms[(u + 3) & 3][16] = smats_lc[(dir * NG + cp) * B + b];
            }
            const float* Pm = Ms[u & 3];
            float n0, n1, n2, n3;
            if (dir == 0) {
                n0 = (v0 * Pm[0] + v1 * Pm[4]) + (v2 * Pm[8] + v3 * Pm[12]);
                n1 = (v0 * Pm[1] + v1 * Pm[5]) + (v2 * Pm[9] + v3 * Pm[13]);
                n2 = (v0 * Pm[2] + v1 * Pm[6]) + (v2 * Pm[10] + v3 * Pm[14]);
                n3 = (v0 * Pm[3] + v1 * Pm[7]) + (v2 * Pm[11] + v3 * Pm[15]);
            } else {
                n0 = (Pm[0] * v0 + Pm[1] * v1) + (Pm[2] * v2 + Pm[3] * v3);
                n1 = (Pm[4] * v0 + Pm[5] * v1) + (Pm[6] * v2 + Pm[7] * v3);
                n2 = (Pm[8] * v0 + Pm[9] * v1) + (Pm[10] * v2 + Pm[11] * v3);
                n3 = (Pm[12] * v0 + Pm[13] * v1) + (Pm[14] * v2 + Pm[15] * v3);
            }
            v0 = n0; v1 = n1; v2 = n2; v3 = n3;
            vlc += Pm[16];
            renorm4(v0, v1, v2, v3, vlc);
        }
        if (dir == 0)
            logZ[b] = LOG2(((v0 + v1) + (v2 + v3))) + vlc;  // base-2 logZ
    }

    __syncthreads();

    // ===== Phase C: expand group bounds -> chunk vbounds (2048 items / 1024 thr) =====
#pragma unroll
    for (int it = 0; it < 2; ++it) {
        const int idx = tid + 1024 * it;
        const int bb = idx & 63;
        const int dd = (idx >> 6) & 1;
        const int g = idx >> 7; // 0..15

        float v0 = gb_p[((dd * NG + g) * 4 + 0) * B + bb];
        float v1 = gb_p[((dd * NG + g) * 4 + 1) * B + bb];
        float v2 = gb_p[((dd * NG + g) * 4 + 2) * B + bb];
        float v3 = gb_p[((dd * NG + g) * 4 + 3) * B + bb];
        float lc = gb_lc[(dd * NG + g) * B + bb];

        if (dd == 0) {
            // fwd: vbound[4g+r] = gbound · M_{4g} ... M_{4g+r-1}
#pragma unroll
            for (int r = 0; r < 4; ++r) {
                const int c = 4 * g + r;
                vbound_p[(c * 4 + 0) * B + bb] = v0;
                vbound_p[(c * 4 + 1) * B + bb] = v1;
                vbound_p[(c * 4 + 2) * B + bb] = v2;
                vbound_p[(c * 4 + 3) * B + bb] = v3;
                vbound_lc[c * B + bb] = lc;
                if (r < 3) {
                    float Mq[16];
#pragma unroll
                    for (int k = 0; k < 16; ++k)
                        Mq[k] = mats_p[(c * 16 + k) * B + bb];
                    lc += mats_lc[c * B + bb];
                    const float n0 = (v0 * Mq[0] + v1 * Mq[4]) + (v2 * Mq[8] + v3 * Mq[12]);
                    const float n1 = (v0 * Mq[1] + v1 * Mq[5]) + (v2 * Mq[9] + v3 * Mq[13]);
                    const float n2 = (v0 * Mq[2] + v1 * Mq[6]) + (v2 * Mq[10] + v3 * Mq[14]);
                    const float n3 = (v0 * Mq[3] + v1 * Mq[7]) + (v2 * Mq[11] + v3 * Mq[15]);
                    v0 = n0; v1 = n1; v2 = n2; v3 = n3;
                    renorm4(v0, v1, v2, v3, lc);
                }
            }
        } else {
            // bwd: vbound[4g+r] = M^b_{4g+r+1} ... M^b_{4g+3} · gbound
#pragma unroll
            for (int r = 3; r >= 0; --r) {
                const int c = 4 * g + r;
                vbound_p[((NCH + c) * 4 + 0) * B + bb] = v0;
                vbound_p[((NCH + c) * 4 + 1) * B + bb] = v1;
                vbound_p[((NCH + c) * 4 + 2) * B + bb] = v2;
                vbound_p[((NCH + c) * 4 + 3) * B + bb] = v3;
                vbound_lc[(NCH + c) * B + bb] = lc;
                if (r > 0) {
                    float Mq[16];
#pragma unroll
                    for (int k = 0; k < 16; ++k)
                        Mq[k] = mats_p[((NCH + c) * 16 + k) * B + bb];
                    lc += mats_lc[(NCH + c) * B + bb];
                    const float n0 = (Mq[0] * v0 + Mq[1] * v1) + (Mq[2] * v2 + Mq[3] * v3);
                    const float n1 = (Mq[4] * v0 + Mq[5] * v1) + (Mq[6] * v2 + Mq[7] * v3);
                    const float n2 = (Mq[8] * v0 + Mq[9] * v1) + (Mq[10] * v2 + Mq[11] * v3);
                    const float n3 = (Mq[12] * v0 + Mq[13] * v1) + (Mq[14] * v2 + Mq[15] * v3);
                    v0 = n0; v1 = n1; v2 = n2; v3 = n3;
                    renorm4(v0, v1, v2, v3, lc);
                }
            }
        }
    }
}

// ---------------- Kernel 4: prob-space rescan of chunk [16c..16c+15] -> sp + chunk sums
__global__ __launch_bounds__(128) void rescan_sp_kernel(
    const float4* __restrict__ pfeatsT, const int* __restrict__ seq_lens,
    const float* __restrict__ T, const float* __restrict__ vbound_p,
    const float* __restrict__ vbound_lc, const float* __restrict__ logZ,
    float* __restrict__ spu, float* __restrict__ chunksum)
{
    const int tid = threadIdx.x;
    const int b = tid & 63;
    const int dir = tid >> 6;
    const int c = blockIdx.x;
    const int sl = seq_lens[b];
    const int base = c * CS;

    float eT2[4][4];
#pragma unroll
    for (int i = 0; i < 4; ++i)
#pragma unroll
        for (int j = 0; j < 4; ++j) eT2[i][j] = EXP2(T[i * 4 + j] * LOG2E);

    __shared__ float ldb_p[CS * 64];
    __shared__ float ldb_lc[CS * 64];

    if (dir == 1) {
        float v0 = vbound_p[((NCH + c) * 4 + 0) * B + b];
        float v1 = vbound_p[((NCH + c) * 4 + 1) * B + b];
        float v2 = vbound_p[((NCH + c) * 4 + 2) * B + b];
        float v3 = vbound_p[((NCH + c) * 4 + 3) * B + b];
        float blc = vbound_lc[(NCH + c) * B + b];
        const bool last = (c == NCH - 1);
        const int hi_n = last ? (L - 1) : (base + CS);
        const int cnt = last ? (CS - 1) : CS;
        if (last) { ldb_p[15 * 64 + b] = v1; ldb_lc[15 * 64 + b] = blc; }
        float4 fr[CS];
#pragma unroll
        for (int u = 0; u < CS; ++u) fr[u] = pfeatsT[max(hi_n - u, base + 1) * B + b];
#pragma unroll
        for (int u = 0; u < CS; ++u) {
            if (u < cnt) {
                const int n = hi_n - u;
                const bool valid = n < sl;
                const float4 f = fr[u];
                const float c0 = f.x * v0, c1 = f.y * v1, c2 = f.z * v2, c3 = f.w * v3;
                const float n0 = (eT2[0][0] * c0 + eT2[0][1] * c1) + (eT2[0][2] * c2 + eT2[0][3] * c3);
                const float n1 = (eT2[1][0] * c0 + eT2[1][1] * c1) + (eT2[1][2] * c2 + eT2[1][3] * c3);
                const float n2 = (eT2[2][0] * c0 + eT2[2][1] * c1) + (eT2[2][2] * c2 + eT2[2][3] * c3);
                const float n3 = (eT2[3][0] * c0 + eT2[3][1] * c1) + (eT2[3][2] * c2 + eT2[3][3] * c3);
                v0 = valid ? n0 : v0; v1 = valid ? n1 : v1;
                v2 = valid ? n2 : v2; v3 = valid ? n3 : v3;
                if ((u & 3) == 3) renorm4(v0, v1, v2, v3, blc);
                ldb_p[(n - 1 - base) * 64 + b] = v1;
                ldb_lc[(n - 1 - base) * 64 + b] = blc;
            }
        }
    }

    float av_p[CS], av_lc[CS];
    if (dir == 0) {
        float a0 = vbound_p[(c * 4 + 0) * B + b];
        float a1 = vbound_p[(c * 4 + 1) * B + b];
        float a2 = vbound_p[(c * 4 + 2) * B + b];
        float a3 = vbound_p[(c * 4 + 3) * B + b];
        float alc = vbound_lc[c * B + b];
        av_p[0] = a1; av_lc[0] = alc;
        float4 fr[CS - 1];
#pragma unroll
        for (int u = 1; u < CS; ++u) fr[u - 1] = pfeatsT[(base + u) * B + b];
#pragma unroll
        for (int u = 1; u < CS; ++u) {
            const int t = base + u;
            const bool valid = t < sl;
            const float4 f = fr[u - 1];
            const float s0 = (a0 * eT2[0][0] + a1 * eT2[1][0]) + (a2 * eT2[2][0] + a3 * eT2[3][0]);
            const float s1 = (a0 * eT2[0][1] + a1 * eT2[1][1]) + (a2 * eT2[2][1] + a3 * eT2[3][1]);
            const float s2 = (a0 * eT2[0][2] + a1 * eT2[1][2]) + (a2 * eT2[2][2] + a3 * eT2[3][2]);
            const float s3 = (a0 * eT2[0][3] + a1 * eT2[1][3]) + (a2 * eT2[2][3] + a3 * eT2[3][3]);
            const float n0 = s0 * f.x, n1 = s1 * f.y, n2 = s2 * f.z, n3 = s3 * f.w;
            a0 = valid ? n0 : a0; a1 = valid ? n1 : a1;
            a2 = valid ? n2 : a2; a3 = valid ? n3 : a3;
            if ((u & 3) == 3) renorm4(a0, a1, a2, a3, alc);
            av_p[u] = a1; av_lc[u] = alc;
        }
    }

    __syncthreads();

    if (dir == 0) {
        const float lz = logZ[b];
        float sp[CS];
        float local = 0.f;
#pragma unroll
        for (int u = 0; u < CS; ++u) {
            const int l = base + u;
            const float x = (l < sl)
                ? av_p[u] * ldb_p[u * 64 + b] * EXP2(av_lc[u] + ldb_lc[u * 64 + b] - lz)
                : 0.f;
            sp[u] = x;
            local += x;
        }
        float4* dst = reinterpret_cast<float4*>(spu + b * L + base);
#pragma unroll
        for (int q = 0; q < 4; ++q)
            dst[q] = make_float4(sp[4 * q], sp[4 * q + 1], sp[4 * q + 2], sp[4 * q + 3]);
        chunksum[c * 64 + b] = local;
    }
}

// ---------------- Kernel 5: sent_vs direct + sprob normalize + scalar (final fused)
__global__ __launch_bounds__(256) void sentv_kernel(
    const float* __restrict__ hidden, const float* __restrict__ spu,
    const float* __restrict__ chunksum, const float* __restrict__ T,
    float* __restrict__ out, float* __restrict__ sprob)
{
    const int hc = blockIdx.x;   // 0..2
    const int b  = blockIdx.y;   // 0..63
    const int tid = threadIdx.x;
    const int lane = tid & 63;
    const int w = tid >> 6;

    __shared__ float s_tot;
    if (tid < 64) {
        float v = chunksum[tid * 64 + b];
#pragma unroll
        for (int s = 32; s >= 1; s >>= 1) v += __shfl_xor(v, s, 64);
        if (tid == 0) s_tot = v;
    }
    __syncthreads();
    const float inv = 2.0f / s_tot;  // == 1/gamma

    const float4* hb = reinterpret_cast<const float4*>(hidden + ((size_t)b * L) * H + hc * 256) + lane;
    const float* sp = spu + b * L;

    float4 acc = make_float4(0.f, 0.f, 0.f, 0.f);
#pragma unroll 8
    for (int i = 0; i < 256; ++i) {
        const int l = w + 4 * i;
        const float s = sp[l];
        const float4 h = hb[(size_t)l * (H / 4)];
        acc.x = fmaf(s, h.x, acc.x); acc.y = fmaf(s, h.y, acc.y);
        acc.z = fmaf(s, h.z, acc.z); acc.w = fmaf(s, h.w, acc.w);
    }

    __shared__ float4 red[4][64];
    red[w][lane] = acc;
    __syncthreads();
    if (tid < 64) {
        const float4 a0 = red[0][lane], a1 = red[1][lane], a2 = red[2][lane], a3 = red[3][lane];
        float4 r;
        r.x = ((a0.x + a1.x) + (a2.x + a3.x)) * inv;
        r.y = ((a0.y + a1.y) + (a2.y + a3.y)) * inv;
        r.z = ((a0.z + a1.z) + (a2.z + a3.z)) * inv;
        r.w = ((a0.w + a1.w) + (a2.w + a3.w)) * inv;
        reinterpret_cast<float4*>(out + (size_t)b * H + hc * 256)[lane] = r;
    }

    if (hc == 0) {
#pragma unroll
        for (int q = 0; q < 4; ++q) {
            const int l = tid + q * 256;
            sprob[b * L + l] = sp[l] * inv;
        }
        if (b == 0 && tid == 0) {
            const float pena = fmaxf(T[4] - T[0], 0.f) + fmaxf(T[1] - T[5], 0.f);
            out[B * H] = 0.1f * pena + 0.1f * 2.0f;  // sum|s_prob| == 2 analytically
        }
    }
}

extern "C" void kernel_launch(void* const* d_in, const int* in_sizes, int n_in,
                              void* d_out, int out_size, void* d_ws, size_t ws_size,
                              hipStream_t stream) {
    const float* hidden   = (const float*)d_in[0];
    const int*   seq_lens = (const int*)d_in[4];
    const float* w        = (const float*)d_in[7];
    const float* bias     = (const float*)d_in[8];
    const float* T        = (const float*)d_in[9];

    float* ws = (float*)d_ws;
    float4* pfeatsT    = (float4*)(ws);          // 262144 floats
    float*  mats_p     = ws + 262144;            // 131072
    float*  mats_lc    = ws + 393216;            // 8192
    float*  smats_p    = ws + 401408;            // 32768
    float*  smats_lc   = ws + 434176;            // 2048
    float*  vbound_p   = ws + 436224;            // 32768
    float*  vbound_lc  = ws + 468992;            // 8192
    float*  logZ       = ws + 477184;            // 64
    float*  chunksum   = ws + 477248;            // 4096
    float*  spu        = ws + 481344;            // 65536

    float* out   = (float*)d_out;
    float* sprob = out + B * H + 1;

    feats_kernel<<<2048, 256, 0, stream>>>(hidden, w, bias, pfeatsT);
    chunkmat_kernel<<<NCH, 128, 0, stream>>>((const float4*)pfeatsT, seq_lens, T, mats_p, mats_lc);
    bound2_kernel<<<1, 1024, 0, stream>>>((const float4*)pfeatsT, mats_p, mats_lc,
                                          smats_p, smats_lc, vbound_p, vbound_lc, logZ);
    rescan_sp_kernel<<<NCH, 128, 0, stream>>>((const float4*)pfeatsT, seq_lens, T,
                                              vbound_p, vbound_lc, logZ, spu, chunksum);
    sentv_kernel<<<dim3(3, 64), 256, 0, stream>>>(hidden, spu, chunksum, T, out, sprob);
}

// Round 11
// 85.622 us; speedup vs baseline: 1.1035x; 1.1035x over previous
//
#include <hip/hip_runtime.h>

#define B 64
#define L 1024
#define H 768
#define NROWS (B * L)
#define LOG2E 1.4426950408889634f
#define CS 16
#define NCH 64
#define NG 16

#define EXP2(x) __builtin_amdgcn_exp2f(x)
#define LOG2(x) __builtin_amdgcn_logf(x)

// Exact power-of-2 renormalization: value = p * 2^lc kept invariant.
__device__ __forceinline__ void renorm4(float& x0, float& x1, float& x2, float& x3, float& lc) {
    const float g = fmaxf(fmaxf(x0, x1), fmaxf(x2, x3));
    const int e = (__float_as_int(g) >> 23) & 255;
    const float s = __int_as_float((254 - e) << 23);
    x0 *= s; x1 *= s; x2 *= s; x3 *= s;
    lc += (float)(e - 127);
}

// ---------------- Kernel 1: pfeatsT[l][b][k] = 2^((hidden.w + bias) * log2e)
__global__ __launch_bounds__(256) void feats_kernel(
    const float* __restrict__ hidden, const float* __restrict__ w,
    const float* __restrict__ bias, float4* __restrict__ pfeatsT)
{
    const int lane = threadIdx.x & 63;
    const int wave = (blockIdx.x * blockDim.x + threadIdx.x) >> 6;
    const int nwaves = (gridDim.x * blockDim.x) >> 6;

    float wr[3][4][4];
#pragma unroll
    for (int c = 0; c < 3; ++c)
#pragma unroll
        for (int j = 0; j < 4; ++j)
#pragma unroll
            for (int k = 0; k < 4; ++k)
                wr[c][j][k] = w[k * H + lane * 4 + 256 * c + j];
    const float bb0 = bias[0], bb1 = bias[1], bb2 = bias[2], bb3 = bias[3];

    for (int row = wave; row < NROWS; row += nwaves) {
        const float4* hrow = reinterpret_cast<const float4*>(hidden) + (size_t)row * (H / 4);
        float acc[4] = {0.f, 0.f, 0.f, 0.f};
#pragma unroll
        for (int c = 0; c < 3; ++c) {
            float4 h = hrow[lane + 64 * c];
            const float hv[4] = {h.x, h.y, h.z, h.w};
#pragma unroll
            for (int j = 0; j < 4; ++j)
#pragma unroll
                for (int k = 0; k < 4; ++k)
                    acc[k] = fmaf(hv[j], wr[c][j][k], acc[k]);
        }
#pragma unroll
        for (int k = 0; k < 4; ++k) {
            float v = acc[k];
#pragma unroll
            for (int s = 32; s >= 1; s >>= 1) v += __shfl_xor(v, s, 64);
            acc[k] = v;
        }
        if (lane == 0) {
            const int b = row >> 10, l = row & 1023;
            pfeatsT[l * B + b] = make_float4(EXP2((acc[0] + bb0) * LOG2E),
                                             EXP2((acc[1] + bb1) * LOG2E),
                                             EXP2((acc[2] + bb2) * LOG2E),
                                             EXP2((acc[3] + bb3) * LOG2E));
        }
    }
}

// ---------------- Kernel 2a: per-chunk 4x4 transfer matrices in PROB space
__global__ __launch_bounds__(128) void chunkmat_kernel(
    const float4* __restrict__ pfeatsT, const int* __restrict__ seq_lens,
    const float* __restrict__ T, float* __restrict__ mats_p,
    float* __restrict__ mats_lc)
{
    const int b = threadIdx.x & 63;
    const int dir = threadIdx.x >> 6;
    const int c = blockIdx.x;
    const int sl = seq_lens[b];
    const int lo = c * CS + 1;
    const int hi = min(c * CS + CS, L - 1);
    const int ns = hi - lo + 1;

    float eT2[4][4];
#pragma unroll
    for (int i = 0; i < 4; ++i)
#pragma unroll
        for (int j = 0; j < 4; ++j) eT2[i][j] = EXP2(T[i * 4 + j] * LOG2E);

    float4 fr[CS];
#pragma unroll
    for (int u = 0; u < CS; ++u) {
        const int t = dir ? max(hi - u, lo) : min(lo + u, hi);
        fr[u] = pfeatsT[t * B + b];
    }

    float M[4][4];
#pragma unroll
    for (int i = 0; i < 4; ++i)
#pragma unroll
        for (int j = 0; j < 4; ++j) M[i][j] = (i == j) ? 1.f : 0.f;
    float lc = 0.f;

#pragma unroll
    for (int u = 0; u < CS; ++u) {
        const int pos = dir ? (hi - u) : (lo + u);
        const bool valid = (u < ns) && (pos < sl);
        const float f[4] = {fr[u].x, fr[u].y, fr[u].z, fr[u].w};
        float nM[4][4];
        if (dir == 0) {
#pragma unroll
            for (int i = 0; i < 4; ++i)
#pragma unroll
                for (int j = 0; j < 4; ++j) {
                    const float s = (M[i][0] * eT2[0][j] + M[i][1] * eT2[1][j]) +
                                    (M[i][2] * eT2[2][j] + M[i][3] * eT2[3][j]);
                    nM[i][j] = s * f[j];
                }
        } else {
            float Mg[4][4];
#pragma unroll
            for (int k = 0; k < 4; ++k)
#pragma unroll
                for (int j = 0; j < 4; ++j) Mg[k][j] = f[k] * M[k][j];
#pragma unroll
            for (int i = 0; i < 4; ++i)
#pragma unroll
                for (int j = 0; j < 4; ++j)
                    nM[i][j] = (eT2[i][0] * Mg[0][j] + eT2[i][1] * Mg[1][j]) +
                               (eT2[i][2] * Mg[2][j] + eT2[i][3] * Mg[3][j]);
        }
#pragma unroll
        for (int i = 0; i < 4; ++i)
#pragma unroll
            for (int j = 0; j < 4; ++j) M[i][j] = valid ? nM[i][j] : M[i][j];

        if (u == 7 || u == CS - 1) {
            float g = 0.f;
#pragma unroll
            for (int i = 0; i < 4; ++i)
#pragma unroll
                for (int j = 0; j < 4; ++j) g = fmaxf(g, M[i][j]);
            const int e = (__float_as_int(g) >> 23) & 255;
            const float s = __int_as_float((254 - e) << 23);
#pragma unroll
            for (int i = 0; i < 4; ++i)
#pragma unroll
                for (int j = 0; j < 4; ++j) M[i][j] *= s;
            lc += (float)(e - 127);
        }
    }
#pragma unroll
    for (int i = 0; i < 4; ++i)
#pragma unroll
        for (int j = 0; j < 4; ++j)
            mats_p[((dir * NCH + c) * 16 + i * 4 + j) * B + b] = M[i][j];
    mats_lc[(dir * NCH + c) * B + b] = lc;
}

// ---------------- Kernel 2b: compose 4 chunk mats -> supermat (parallel, 16 blocks)
__global__ __launch_bounds__(128) void groupmat_kernel(
    const float* __restrict__ mats_p, const float* __restrict__ mats_lc,
    float* __restrict__ smats_p, float* __restrict__ smats_lc)
{
    const int b = threadIdx.x & 63;
    const int dir = threadIdx.x >> 6;
    const int g = blockIdx.x; // 0..15

    float P[4][4];
    float lc = 0.f;
    {
        const int c0 = 4 * g;
#pragma unroll
        for (int k = 0; k < 16; ++k)
            P[k >> 2][k & 3] = mats_p[((dir * NCH + c0) * 16 + k) * B + b];
        lc = mats_lc[(dir * NCH + c0) * B + b];
    }

#pragma unroll
    for (int q = 1; q < 4; ++q) {
        const int c = 4 * g + q;
        float Q[4][4];
#pragma unroll
        for (int k = 0; k < 16; ++k)
            Q[k >> 2][k & 3] = mats_p[((dir * NCH + c) * 16 + k) * B + b];
        lc += mats_lc[(dir * NCH + c) * B + b];

        float R[4][4];
#pragma unroll
        for (int i = 0; i < 4; ++i)
#pragma unroll
            for (int j = 0; j < 4; ++j)
                R[i][j] = (P[i][0] * Q[0][j] + P[i][1] * Q[1][j]) +
                          (P[i][2] * Q[2][j] + P[i][3] * Q[3][j]);

        float gmax = 0.f;
#pragma unroll
        for (int i = 0; i < 4; ++i)
#pragma unroll
            for (int j = 0; j < 4; ++j) gmax = fmaxf(gmax, R[i][j]);
        const int e = (__float_as_int(gmax) >> 23) & 255;
        const float s = __int_as_float((254 - e) << 23);
#pragma unroll
        for (int i = 0; i < 4; ++i)
#pragma unroll
            for (int j = 0; j < 4; ++j) P[i][j] = R[i][j] * s;
        lc += (float)(e - 127);
    }

#pragma unroll
    for (int i = 0; i < 4; ++i)
#pragma unroll
        for (int j = 0; j < 4; ++j)
            smats_p[((dir * NG + g) * 16 + i * 4 + j) * B + b] = P[i][j];
    smats_lc[(dir * NG + g) * B + b] = lc;
}

// ---------------- Kernel 2c: serial scan over 16 supermats -> group boundaries, logZ
__global__ __launch_bounds__(128) void bound_kernel(
    const float4* __restrict__ pfeatsT, const float* __restrict__ smats_p,
    const float* __restrict__ smats_lc, float* __restrict__ gbound_p,
    float* __restrict__ gbound_lc, float* __restrict__ logZ)
{
    const int b = threadIdx.x & 63;
    const int dir = threadIdx.x >> 6;

    float Ms[4][17];
#pragma unroll
    for (int p = 0; p < 3; ++p) {
        const int cc = dir ? (NG - 1 - p) : p;
#pragma unroll
        for (int k = 0; k < 16; ++k)
            Ms[p][k] = smats_p[((dir * NG + cc) * 16 + k) * B + b];
        Ms[p][16] = smats_lc[(dir * NG + cc) * B + b];
    }

    float v0, v1, v2, v3, vlc = 0.f;
    if (dir == 0) {
        const float4 f0 = pfeatsT[b];
        v0 = f0.x; v1 = f0.y; v2 = f0.z; v3 = f0.w;
    } else {
        v0 = v1 = v2 = v3 = 1.f;
    }

#pragma unroll
    for (int u = 0; u < NG; ++u) {
        const int cc = dir ? (NG - 1 - u) : u;
        gbound_p[((dir * NG + cc) * 4 + 0) * B + b] = v0;
        gbound_p[((dir * NG + cc) * 4 + 1) * B + b] = v1;
        gbound_p[((dir * NG + cc) * 4 + 2) * B + b] = v2;
        gbound_p[((dir * NG + cc) * 4 + 3) * B + b] = v3;
        gbound_lc[(dir * NG + cc) * B + b] = vlc;
        if (u + 3 < NG) {
            const int cp = dir ? (NG - 1 - (u + 3)) : (u + 3);
#pragma unroll
            for (int k = 0; k < 16; ++k)
                Ms[(u + 3) & 3][k] = smats_p[((dir * NG + cp) * 16 + k) * B + b];
            Ms[(u + 3) & 3][16] = smats_lc[(dir * NG + cp) * B + b];
        }
        const float* Pm = Ms[u & 3];
        float n0, n1, n2, n3;
        if (dir == 0) {
            n0 = (v0 * Pm[0] + v1 * Pm[4]) + (v2 * Pm[8] + v3 * Pm[12]);
            n1 = (v0 * Pm[1] + v1 * Pm[5]) + (v2 * Pm[9] + v3 * Pm[13]);
            n2 = (v0 * Pm[2] + v1 * Pm[6]) + (v2 * Pm[10] + v3 * Pm[14]);
            n3 = (v0 * Pm[3] + v1 * Pm[7]) + (v2 * Pm[11] + v3 * Pm[15]);
        } else {
            n0 = (Pm[0] * v0 + Pm[1] * v1) + (Pm[2] * v2 + Pm[3] * v3);
            n1 = (Pm[4] * v0 + Pm[5] * v1) + (Pm[6] * v2 + Pm[7] * v3);
            n2 = (Pm[8] * v0 + Pm[9] * v1) + (Pm[10] * v2 + Pm[11] * v3);
            n3 = (Pm[12] * v0 + Pm[13] * v1) + (Pm[14] * v2 + Pm[15] * v3);
        }
        v0 = n0; v1 = n1; v2 = n2; v3 = n3;
        vlc += Pm[16];
        renorm4(v0, v1, v2, v3, vlc);
    }
    if (dir == 0)
        logZ[b] = LOG2(((v0 + v1) + (v2 + v3))) + vlc;  // base-2 logZ
}

// ---------------- Kernel 2d: expand group boundary -> chunk entry, replay, sp + sums
__global__ __launch_bounds__(128) void rescan_sp_kernel(
    const float4* __restrict__ pfeatsT, const int* __restrict__ seq_lens,
    const float* __restrict__ T, const float* __restrict__ mats_p,
    const float* __restrict__ mats_lc, const float* __restrict__ gbound_p,
    const float* __restrict__ gbound_lc, const float* __restrict__ logZ,
    float* __restrict__ spu, float* __restrict__ chunksum)
{
    const int tid = threadIdx.x;
    const int b = tid & 63;
    const int dir = tid >> 6;
    const int c = blockIdx.x;
    const int g = c >> 2;
    const int r = c & 3;
    const int sl = seq_lens[b];
    const int base = c * CS;

    float eT2[4][4];
#pragma unroll
    for (int i = 0; i < 4; ++i)
#pragma unroll
        for (int j = 0; j < 4; ++j) eT2[i][j] = EXP2(T[i * 4 + j] * LOG2E);

    __shared__ float ldb_p[CS * 64];
    __shared__ float ldb_lc[CS * 64];

    if (dir == 1) {
        float v0 = gbound_p[((NG + g) * 4 + 0) * B + b];
        float v1 = gbound_p[((NG + g) * 4 + 1) * B + b];
        float v2 = gbound_p[((NG + g) * 4 + 2) * B + b];
        float v3 = gbound_p[((NG + g) * 4 + 3) * B + b];
        float blc = gbound_lc[(NG + g) * B + b];
        for (int q = 3; q > r; --q) {
            const int cq = 4 * g + q;
            float Mq[16];
#pragma unroll
            for (int k = 0; k < 16; ++k)
                Mq[k] = mats_p[((NCH + cq) * 16 + k) * B + b];
            blc += mats_lc[(NCH + cq) * B + b];
            const float n0 = (Mq[0] * v0 + Mq[1] * v1) + (Mq[2] * v2 + Mq[3] * v3);
            const float n1 = (Mq[4] * v0 + Mq[5] * v1) + (Mq[6] * v2 + Mq[7] * v3);
            const float n2 = (Mq[8] * v0 + Mq[9] * v1) + (Mq[10] * v2 + Mq[11] * v3);
            const float n3 = (Mq[12] * v0 + Mq[13] * v1) + (Mq[14] * v2 + Mq[15] * v3);
            v0 = n0; v1 = n1; v2 = n2; v3 = n3;
            renorm4(v0, v1, v2, v3, blc);
        }

        const bool last = (c == NCH - 1);
        const int hi_n = last ? (L - 1) : (base + CS);
        const int cnt = last ? (CS - 1) : CS;
        if (last) { ldb_p[15 * 64 + b] = v1; ldb_lc[15 * 64 + b] = blc; }
        float4 fr[CS];
#pragma unroll
        for (int u = 0; u < CS; ++u) fr[u] = pfeatsT[max(hi_n - u, base + 1) * B + b];
#pragma unroll
        for (int u = 0; u < CS; ++u) {
            if (u < cnt) {
                const int n = hi_n - u;
                const bool valid = n < sl;
                const float4 f = fr[u];
                const float c0 = f.x * v0, c1 = f.y * v1, c2 = f.z * v2, c3 = f.w * v3;
                const float n0 = (eT2[0][0] * c0 + eT2[0][1] * c1) + (eT2[0][2] * c2 + eT2[0][3] * c3);
                const float n1 = (eT2[1][0] * c0 + eT2[1][1] * c1) + (eT2[1][2] * c2 + eT2[1][3] * c3);
                const float n2 = (eT2[2][0] * c0 + eT2[2][1] * c1) + (eT2[2][2] * c2 + eT2[2][3] * c3);
                const float n3 = (eT2[3][0] * c0 + eT2[3][1] * c1) + (eT2[3][2] * c2 + eT2[3][3] * c3);
                v0 = valid ? n0 : v0; v1 = valid ? n1 : v1;
                v2 = valid ? n2 : v2; v3 = valid ? n3 : v3;
                if ((u & 3) == 3) renorm4(v0, v1, v2, v3, blc);
                ldb_p[(n - 1 - base) * 64 + b] = v1;
                ldb_lc[(n - 1 - base) * 64 + b] = blc;
            }
        }
    }

    float av_p[CS], av_lc[CS];
    if (dir == 0) {
        float a0 = gbound_p[(g * 4 + 0) * B + b];
        float a1 = gbound_p[(g * 4 + 1) * B + b];
        float a2 = gbound_p[(g * 4 + 2) * B + b];
        float a3 = gbound_p[(g * 4 + 3) * B + b];
        float alc = gbound_lc[g * B + b];
        for (int q = 0; q < r; ++q) {
            const int cq = 4 * g + q;
            float Mq[16];
#pragma unroll
            for (int k = 0; k < 16; ++k)
                Mq[k] = mats_p[(cq * 16 + k) * B + b];
            alc += mats_lc[cq * B + b];
            const float n0 = (a0 * Mq[0] + a1 * Mq[4]) + (a2 * Mq[8] + a3 * Mq[12]);
            const float n1 = (a0 * Mq[1] + a1 * Mq[5]) + (a2 * Mq[9] + a3 * Mq[13]);
            const float n2 = (a0 * Mq[2] + a1 * Mq[6]) + (a2 * Mq[10] + a3 * Mq[14]);
            const float n3 = (a0 * Mq[3] + a1 * Mq[7]) + (a2 * Mq[11] + a3 * Mq[15]);
            a0 = n0; a1 = n1; a2 = n2; a3 = n3;
            renorm4(a0, a1, a2, a3, alc);
        }

        av_p[0] = a1; av_lc[0] = alc;
        float4 fr[CS - 1];
#pragma unroll
        for (int u = 1; u < CS; ++u) fr[u - 1] = pfeatsT[(base + u) * B + b];
#pragma unroll
        for (int u = 1; u < CS; ++u) {
            const int t = base + u;
            const bool valid = t < sl;
            const float4 f = fr[u - 1];
            const float s0 = (a0 * eT2[0][0] + a1 * eT2[1][0]) + (a2 * eT2[2][0] + a3 * eT2[3][0]);
            const float s1 = (a0 * eT2[0][1] + a1 * eT2[1][1]) + (a2 * eT2[2][1] + a3 * eT2[3][1]);
            const float s2 = (a0 * eT2[0][2] + a1 * eT2[1][2]) + (a2 * eT2[2][2] + a3 * eT2[3][2]);
            const float s3 = (a0 * eT2[0][3] + a1 * eT2[1][3]) + (a2 * eT2[2][3] + a3 * eT2[3][3]);
            const float n0 = s0 * f.x, n1 = s1 * f.y, n2 = s2 * f.z, n3 = s3 * f.w;
            a0 = valid ? n0 : a0; a1 = valid ? n1 : a1;
            a2 = valid ? n2 : a2; a3 = valid ? n3 : a3;
            if ((u & 3) == 3) renorm4(a0, a1, a2, a3, alc);
            av_p[u] = a1; av_lc[u] = alc;
        }
    }

    __syncthreads();

    if (dir == 0) {
        const float lz = logZ[b];
        float sp[CS];
        float local = 0.f;
#pragma unroll
        for (int u = 0; u < CS; ++u) {
            const int l = base + u;
            const float x = (l < sl)
                ? av_p[u] * ldb_p[u * 64 + b] * EXP2(av_lc[u] + ldb_lc[u * 64 + b] - lz)
                : 0.f;
            sp[u] = x;
            local += x;
        }
        float4* dst = reinterpret_cast<float4*>(spu + b * L + base);
#pragma unroll
        for (int q = 0; q < 4; ++q)
            dst[q] = make_float4(sp[4 * q], sp[4 * q + 1], sp[4 * q + 2], sp[4 * q + 3]);
        chunksum[c * 64 + b] = local;
    }
}

// ---------------- Kernel 3: fused sent_vs + gamma + sprob + scalar
// grid (3, 64) x 1024 threads: 16 waves/block, 3072 waves total.
__global__ __launch_bounds__(1024) void sentv_final_kernel(
    const float* __restrict__ hidden, const float* __restrict__ spu,
    const float* __restrict__ chunksum, const float* __restrict__ T,
    float* __restrict__ out, float* __restrict__ sprob)
{
    const int hc = blockIdx.x;   // 0..2, 256-float column slab
    const int b  = blockIdx.y;   // 0..63
    const int tid = threadIdx.x;
    const int lane = tid & 63;
    const int w = tid >> 6;      // 0..15

    __shared__ float s_tot;
    if (tid < 64) {
        float v = chunksum[tid * 64 + b];
#pragma unroll
        for (int s = 32; s >= 1; s >>= 1) v += __shfl_xor(v, s, 64);
        if (tid == 0) s_tot = v;
    }
    __syncthreads();
    const float inv = 2.0f / s_tot;  // == 1/gamma

    const float4* hb = reinterpret_cast<const float4*>(hidden) +
                       (size_t)b * L * (H / 4) + hc * 64;
    const float* sp = spu + b * L;

    float4 acc = make_float4(0.f, 0.f, 0.f, 0.f);
#pragma unroll 8
    for (int i = 0; i < 64; ++i) {
        const int l = w + 16 * i;
        const float s = sp[l];
        const float4 h = hb[(size_t)l * (H / 4) + lane];
        acc.x = fmaf(s, h.x, acc.x); acc.y = fmaf(s, h.y, acc.y);
        acc.z = fmaf(s, h.z, acc.z); acc.w = fmaf(s, h.w, acc.w);
    }

    __shared__ float4 red[16][64];
    red[w][lane] = acc;
    __syncthreads();
    if (tid < 64) {
        float4 r = make_float4(0.f, 0.f, 0.f, 0.f);
#pragma unroll
        for (int q = 0; q < 16; q += 4) {
            const float4 a0 = red[q][lane], a1 = red[q + 1][lane];
            const float4 a2 = red[q + 2][lane], a3 = red[q + 3][lane];
            r.x += (a0.x + a1.x) + (a2.x + a3.x);
            r.y += (a0.y + a1.y) + (a2.y + a3.y);
            r.z += (a0.z + a1.z) + (a2.z + a3.z);
            r.w += (a0.w + a1.w) + (a2.w + a3.w);
        }
        r.x *= inv; r.y *= inv; r.z *= inv; r.w *= inv;
        reinterpret_cast<float4*>(out)[(size_t)b * (H / 4) + hc * 64 + lane] = r;
    }

    if (hc == 0) {
        sprob[b * L + tid] = sp[tid] * inv;  // 1024 threads cover the row
        if (b == 0 && tid == 0) {
            const float pena = fmaxf(T[4] - T[0], 0.f) + fmaxf(T[1] - T[5], 0.f);
            out[B * H] = 0.1f * pena + 0.1f * 2.0f;  // sum|s_prob| == 2 analytically
        }
    }
}

extern "C" void kernel_launch(void* const* d_in, const int* in_sizes, int n_in,
                              void* d_out, int out_size, void* d_ws, size_t ws_size,
                              hipStream_t stream) {
    const float* hidden   = (const float*)d_in[0];
    const int*   seq_lens = (const int*)d_in[4];
    const float* w        = (const float*)d_in[7];
    const float* bias     = (const float*)d_in[8];
    const float* T        = (const float*)d_in[9];

    float* ws = (float*)d_ws;
    float4* pfeatsT    = (float4*)(ws);          // 262144 floats
    float*  mats_p     = ws + 262144;            // 131072
    float*  mats_lc    = ws + 393216;            // 8192
    float*  smats_p    = ws + 401408;            // 32768
    float*  smats_lc   = ws + 434176;            // 2048
    float*  gbound_p   = ws + 436224;            // 8192
    float*  gbound_lc  = ws + 444416;            // 2048
    float*  logZ       = ws + 446464;            // 64
    float*  chunksum   = ws + 446528;            // 4096
    float*  spu        = ws + 450624;            // 65536

    float* out   = (float*)d_out;
    float* sprob = out + B * H + 1;

    feats_kernel<<<2048, 256, 0, stream>>>(hidden, w, bias, pfeatsT);
    chunkmat_kernel<<<NCH, 128, 0, stream>>>((const float4*)pfeatsT, seq_lens, T, mats_p, mats_lc);
    groupmat_kernel<<<NG, 128, 0, stream>>>(mats_p, mats_lc, smats_p, smats_lc);
    bound_kernel<<<1, 128, 0, stream>>>((const float4*)pfeatsT, smats_p, smats_lc,
                                        gbound_p, gbound_lc, logZ);
    rescan_sp_kernel<<<NCH, 128, 0, stream>>>((const float4*)pfeatsT, seq_lens, T,
                                              mats_p, mats_lc, gbound_p, gbound_lc,
                                              logZ, spu, chunksum);
    sentv_final_kernel<<<dim3(3, 64), 1024, 0, stream>>>(hidden, spu, chunksum, T, out, sprob);
}